// Round 1
// baseline (275.164 us; speedup 1.0000x reference)
//
#include <hip/hip_runtime.h>
#include <math.h>

#define NV 720
#define NU 736
#define NXY 512

// fp32 geometry constants (rounded from f64 exactly as the reference's weak-typed
// scalars are when they meet f32 arrays)
__device__ __forceinline__ float f_du()    { return (float)1.2858; }
__device__ __forceinline__ float f_dsd()   { return (float)(595.0 + 490.6); }      // 1085.6
__device__ __forceinline__ float f_dso()   { return 595.0f; }

// ---------------- Stage 1+2: cosine weight + Ram-Lak direct convolution ----------------
// Ram-Lak spatial kernel: h(0)=1/(4 du^2), h(n)=-1/(pi n du)^2 for odd n, 0 for even n!=0.
// Q[v,j] = du * ( h0*sw[j] + sum_{u parity != j} sw[u] * C/(j-u)^2 ),  C = -1/(pi^2 du^2)
__global__ __launch_bounds__(256) void filter_kernel(const float* __restrict__ sino,
                                                     float* __restrict__ Q) {
    __shared__ float srow[NU];
    __shared__ float inv2[NU];   // inv2[n] = -1/(pi*n*du)^2 for odd n
    const int v = blockIdx.x;
    const int t = threadIdx.x;

    // build odd-offset weight table (f64 per-term, like the reference's f64 h)
    for (int n = t; n < NU; n += 256) {
        float w = 0.0f;
        if (n & 1) {
            double a = M_PI * (double)n * 1.2858;
            w = (float)(-1.0 / (a * a));
        }
        inv2[n] = w;
    }
    // load + cosine weighting:  sw[u] = sino[v,u] * DSD/sqrt(DSD^2 + us^2)
    const float DSD2 = (float)(1085.6 * 1085.6);
    for (int u = t; u < NU; u += 256) {
        float us = ((float)u - 367.5f) * f_du();
        float cw = f_dsd() / sqrtf(DSD2 + us * us);
        srow[u] = sino[v * NU + u] * cw;
    }
    __syncthreads();

    const float H0 = (float)(1.0 / (4.0 * 1.2858 * 1.2858));
    for (int j = t; j < NU; j += 256) {
        float acc = H0 * srow[j];
        const int u0 = (j & 1) ^ 1;          // opposite parity start
        #pragma unroll 8
        for (int i = 0; i < NU / 2; ++i) {   // 368 odd-offset taps
            int u = u0 + 2 * i;
            int d = j - u;
            d = (d < 0) ? -d : d;            // |j-u| is odd
            acc = fmaf(srow[u], inv2[d], acc);
        }
        Q[v * NU + j] = acc * f_du();
    }
}

// ---------------- Stage 3: weighted fan-beam backprojection ----------------
__global__ __launch_bounds__(256) void bp_kernel(const float* __restrict__ Q,
                                                 float* __restrict__ out) {
    __shared__ float cbs[NV], sbs[NV];
    const int t = threadIdx.x;
    for (int v = t; v < NV; v += 256) {
        float beta = (float)((double)v * (2.0 * M_PI / 720.0));
        cbs[v] = cosf(beta);
        sbs[v] = sinf(beta);
    }
    __syncthreads();

    const int p = blockIdx.x * 256 + t;
    const int ix = p >> 9;         // / 512  (X index, row)
    const int jy = p & 511;        // % 512  (Y index, col)
    const float dx = 400.0f / 512.0f;             // 0.78125 exact
    const float X = ((float)ix - 255.5f) * dx;
    const float Y = ((float)jy - 255.5f) * dx;
    const float invDU = (float)(1.0 / 1.2858);

    float acc = 0.0f;
    for (int v = 0; v < NV; ++v) {
        float cb = cbs[v], sb = sbs[v];
        float tt = X * cb + Y * sb;            // detector-direction coord
        float ss = Y * cb - X * sb;            // toward-source coord
        float D  = f_dso() - ss;
        float rD = 1.0f / D;                   // IEEE div, reused for u and weight
        float u  = f_dsd() * tt * rD;
        float fidx = u * invDU + 367.5f;
        float fl = floorf(fidx);
        int i0 = (int)fl;
        i0 = (i0 < 0) ? 0 : ((i0 > NU - 2) ? NU - 2 : i0);
        float f = fidx - (float)i0;
        const float* qr = Q + v * NU;
        float q0 = qr[i0];
        float q1 = qr[i0 + 1];
        float val = q0 * (1.0f - f) + q1 * f;
        bool inb = (fidx >= 0.0f) && (fidx <= (float)(NU - 1));
        val = inb ? val : 0.0f;
        float w = f_dso() * rD;
        acc += (w * w) * val;
    }
    out[p] = acc * (float)(0.5 * (2.0 * M_PI / 720.0));   // 0.5*dbeta
}

extern "C" void kernel_launch(void* const* d_in, const int* in_sizes, int n_in,
                              void* d_out, int out_size, void* d_ws, size_t ws_size,
                              hipStream_t stream) {
    const float* sino = (const float*)d_in[0];
    float* out = (float*)d_out;
    float* Q = (float*)d_ws;                 // 720*736*4 B = 2.12 MB scratch

    filter_kernel<<<NV, 256, 0, stream>>>(sino, Q);
    bp_kernel<<<(NXY * NXY) / 256, 256, 0, stream>>>(Q, out);
}

// Round 2
// 187.316 us; speedup vs baseline: 1.4690x; 1.4690x over previous
//
#include <hip/hip_runtime.h>
#include <math.h>

#define NV 720
#define NU 736
#define NXY 512

// ---------------- trig tables: {cb*DSD/DU, sb*DSD/DU, cb, sb} per view ----------------
__global__ __launch_bounds__(256) void trig_kernel(float4* __restrict__ trig) {
    int v = blockIdx.x * 256 + threadIdx.x;
    if (v < NV) {
        float beta = (float)((double)v * (2.0 * M_PI / 720.0));
        float cb = cosf(beta), sb = sinf(beta);
        const float K = (float)(1085.6 / 1.2858);   // DSD/DU
        trig[v] = make_float4(cb * K, sb * K, cb, sb);
    }
}

// ---------------- Stage 1+2: cosine weight + Ram-Lak as register-tiled Toeplitz GEMM ----
// Q[v,j] = DU * ( H0*sw[v,j] + sum_m sw[v, 2m+q] * wco[(j-(2m+q)+735)/2] ),  q = 1-(j&1)
// Block: 4 views, 192 threads; active thread -> 4 same-parity outputs x 4 views.
// Reduction index m is wave-uniform => sinogram read is a broadcast b128;
// weight reads are lane-consecutive b32 (conflict-free) at imm offsets {0,368,736,1104}B.
__global__ __launch_bounds__(192) void filter_kernel(const float* __restrict__ sino,
                                                     float* __restrict__ Q) {
    __shared__ float s4[2][368][4];   // [parity][m][view]  (cosine-weighted sino)
    __shared__ float wco[736];        // wco[i] = -1/(pi*(2i-735)*DU)^2   (2i-735 always odd)
    const int v0 = blockIdx.x * 4;
    const int t = threadIdx.x;

    for (int i = t; i < 736; i += 192) {
        double n = (double)(2 * i - 735);
        double a = M_PI * n * 1.2858;
        wco[i] = (float)(-1.0 / (a * a));
    }
    const float DSD2 = (float)(1085.6 * 1085.6);
    for (int vv = 0; vv < 4; ++vv) {
        for (int u = t; u < 736; u += 192) {
            float us = ((float)u - 367.5f) * 1.2858f;
            float cw = 1085.6f / sqrtf(DSD2 + us * us);
            s4[u & 1][u >> 1][vv] = sino[(v0 + vv) * NU + u] * cw;
        }
    }
    __syncthreads();

    if (t < 184) {
        const int pj = (t < 92) ? 1 : 0;       // thread group -> output parity
        const int J0 = (t < 92) ? t : t - 92;
        const int q = 1 - pj;                  // input parity
        float acc[4][4];
        #pragma unroll
        for (int r = 0; r < 4; ++r)
            #pragma unroll
            for (int vv = 0; vv < 4; ++vv) acc[r][vv] = 0.0f;

        const int ibase0 = J0 + 367 + pj;      // w index at m=0, r=0
        #pragma unroll 4
        for (int m = 0; m < 368; ++m) {
            const float4 sv = *(const float4*)&s4[q][m][0];   // broadcast
            const int ib = ibase0 - m;
            const float w0 = wco[ib];
            const float w1 = wco[ib + 92];
            const float w2 = wco[ib + 184];
            const float w3 = wco[ib + 276];
            acc[0][0] = fmaf(w0, sv.x, acc[0][0]);
            acc[0][1] = fmaf(w0, sv.y, acc[0][1]);
            acc[0][2] = fmaf(w0, sv.z, acc[0][2]);
            acc[0][3] = fmaf(w0, sv.w, acc[0][3]);
            acc[1][0] = fmaf(w1, sv.x, acc[1][0]);
            acc[1][1] = fmaf(w1, sv.y, acc[1][1]);
            acc[1][2] = fmaf(w1, sv.z, acc[1][2]);
            acc[1][3] = fmaf(w1, sv.w, acc[1][3]);
            acc[2][0] = fmaf(w2, sv.x, acc[2][0]);
            acc[2][1] = fmaf(w2, sv.y, acc[2][1]);
            acc[2][2] = fmaf(w2, sv.z, acc[2][2]);
            acc[2][3] = fmaf(w2, sv.w, acc[2][3]);
            acc[3][0] = fmaf(w3, sv.x, acc[3][0]);
            acc[3][1] = fmaf(w3, sv.y, acc[3][1]);
            acc[3][2] = fmaf(w3, sv.z, acc[3][2]);
            acc[3][3] = fmaf(w3, sv.w, acc[3][3]);
        }
        // central tap: + H0 * sw[v, j]
        const float H0 = (float)(1.0 / (4.0 * 1.2858 * 1.2858));
        #pragma unroll
        for (int r = 0; r < 4; ++r) {
            const float4 c = *(const float4*)&s4[pj][J0 + 92 * r][0];
            acc[r][0] = fmaf(H0, c.x, acc[r][0]);
            acc[r][1] = fmaf(H0, c.y, acc[r][1]);
            acc[r][2] = fmaf(H0, c.z, acc[r][2]);
            acc[r][3] = fmaf(H0, c.w, acc[r][3]);
        }
        #pragma unroll
        for (int r = 0; r < 4; ++r) {
            const int j = 2 * (J0 + 92 * r) + pj;
            #pragma unroll
            for (int vv = 0; vv < 4; ++vv)
                Q[(v0 + vv) * NU + j] = acc[r][vv] * 1.2858f;
        }
    }
}

// ---------------- Stage 3: weighted fan-beam backprojection (instruction diet) ----------
__global__ __launch_bounds__(256) void bp_kernel(const float* __restrict__ Q,
                                                 const float4* __restrict__ trig,
                                                 float* __restrict__ out) {
    const int p = blockIdx.x * 256 + threadIdx.x;
    const int ix = p >> 9;
    const int jy = p & 511;
    const float dx = 400.0f / 512.0f;   // 0.78125 exact
    const float X  = ((float)ix - 255.5f) * dx;
    const float Y  = ((float)jy - 255.5f) * dx;
    const float nY = -Y;

    float acc = 0.0f;
    const float* qrow = Q;
    #pragma unroll 4
    for (int v = 0; v < NV; ++v) {
        const float4 tv = trig[v];                 // uniform -> s_load_dwordx4
        float t2 = fmaf(tv.x, X, tv.y * Y);        // t * DSD/DU
        float e  = fmaf(tv.w, X, fmaf(tv.z, nY, 595.0f));   // D = DSO - s
        float rD = __builtin_amdgcn_rcpf(e);       // 1-ulp v_rcp_f32
        float fidx = fmaf(t2, rD, 367.5f);
        int i0 = (int)fidx;                        // trunc == floor for fidx>=0; <0 masked
        int i0c = min(max(i0, 0), NU - 2);         // v_med3_i32
        float f = fidx - (float)i0c;
        float q0 = qrow[i0c];
        float q1 = qrow[i0c + 1];
        float val = fmaf(f, q1 - q0, q0);
        float g = rD * rD;
        g = (fidx >= 0.0f && fidx <= 735.0f) ? g : 0.0f;
        acc = fmaf(g, val, acc);
        qrow += NU;
    }
    // DSO^2 * 0.5 * dbeta folded into one epilogue constant
    out[p] = acc * (float)(595.0 * 595.0 * 0.5 * (2.0 * M_PI / 720.0));
}

extern "C" void kernel_launch(void* const* d_in, const int* in_sizes, int n_in,
                              void* d_out, int out_size, void* d_ws, size_t ws_size,
                              hipStream_t stream) {
    const float* sino = (const float*)d_in[0];
    float* out = (float*)d_out;
    float* Q = (float*)d_ws;                                  // 720*736*4 = 2.12 MB
    float4* trig = (float4*)((char*)d_ws + NV * NU * sizeof(float));  // +11.5 KB

    trig_kernel<<<3, 256, 0, stream>>>(trig);
    filter_kernel<<<NV / 4, 192, 0, stream>>>(sino, Q);
    bp_kernel<<<(NXY * NXY) / 256, 256, 0, stream>>>(Q, trig, out);
}

// Round 3
// 164.705 us; speedup vs baseline: 1.6706x; 1.1373x over previous
//
#include <hip/hip_runtime.h>
#include <math.h>

#define NV 720
#define NU 736
#define NXY 512

// ---------------- trig tables: {cb*DSD/DU, sb*DSD/DU, cb, sb} per view ----------------
__global__ __launch_bounds__(256) void trig_kernel(float4* __restrict__ trig) {
    int v = blockIdx.x * 256 + threadIdx.x;
    if (v < NV) {
        float beta = (float)((double)v * (2.0 * M_PI / 720.0));
        float cb = cosf(beta), sb = sinf(beta);
        const float K = (float)(1085.6 / 1.2858);   // DSD/DU
        trig[v] = make_float4(cb * K, sb * K, cb, sb);
    }
}

// ---------------- Stage 1+2: cosine weight + Ram-Lak as register-tiled Toeplitz GEMM ----
// (unchanged from R2 — measured fast; total-bp gap is fixed overhead, not filter)
__global__ __launch_bounds__(192) void filter_kernel(const float* __restrict__ sino,
                                                     float* __restrict__ Q) {
    __shared__ float s4[2][368][4];   // [parity][m][view]
    __shared__ float wco[736];        // wco[i] = -1/(pi*(2i-735)*DU)^2
    const int v0 = blockIdx.x * 4;
    const int t = threadIdx.x;

    for (int i = t; i < 736; i += 192) {
        double n = (double)(2 * i - 735);
        double a = M_PI * n * 1.2858;
        wco[i] = (float)(-1.0 / (a * a));
    }
    const float DSD2 = (float)(1085.6 * 1085.6);
    for (int vv = 0; vv < 4; ++vv) {
        for (int u = t; u < 736; u += 192) {
            float us = ((float)u - 367.5f) * 1.2858f;
            float cw = 1085.6f / sqrtf(DSD2 + us * us);
            s4[u & 1][u >> 1][vv] = sino[(v0 + vv) * NU + u] * cw;
        }
    }
    __syncthreads();

    if (t < 184) {
        const int pj = (t < 92) ? 1 : 0;
        const int J0 = (t < 92) ? t : t - 92;
        const int q = 1 - pj;
        float acc[4][4];
        #pragma unroll
        for (int r = 0; r < 4; ++r)
            #pragma unroll
            for (int vv = 0; vv < 4; ++vv) acc[r][vv] = 0.0f;

        const int ibase0 = J0 + 367 + pj;
        #pragma unroll 4
        for (int m = 0; m < 368; ++m) {
            const float4 sv = *(const float4*)&s4[q][m][0];
            const int ib = ibase0 - m;
            const float w0 = wco[ib];
            const float w1 = wco[ib + 92];
            const float w2 = wco[ib + 184];
            const float w3 = wco[ib + 276];
            acc[0][0] = fmaf(w0, sv.x, acc[0][0]);
            acc[0][1] = fmaf(w0, sv.y, acc[0][1]);
            acc[0][2] = fmaf(w0, sv.z, acc[0][2]);
            acc[0][3] = fmaf(w0, sv.w, acc[0][3]);
            acc[1][0] = fmaf(w1, sv.x, acc[1][0]);
            acc[1][1] = fmaf(w1, sv.y, acc[1][1]);
            acc[1][2] = fmaf(w1, sv.z, acc[1][2]);
            acc[1][3] = fmaf(w1, sv.w, acc[1][3]);
            acc[2][0] = fmaf(w2, sv.x, acc[2][0]);
            acc[2][1] = fmaf(w2, sv.y, acc[2][1]);
            acc[2][2] = fmaf(w2, sv.z, acc[2][2]);
            acc[2][3] = fmaf(w2, sv.w, acc[2][3]);
            acc[3][0] = fmaf(w3, sv.x, acc[3][0]);
            acc[3][1] = fmaf(w3, sv.y, acc[3][1]);
            acc[3][2] = fmaf(w3, sv.z, acc[3][2]);
            acc[3][3] = fmaf(w3, sv.w, acc[3][3]);
        }
        const float H0 = (float)(1.0 / (4.0 * 1.2858 * 1.2858));
        #pragma unroll
        for (int r = 0; r < 4; ++r) {
            const float4 c = *(const float4*)&s4[pj][J0 + 92 * r][0];
            acc[r][0] = fmaf(H0, c.x, acc[r][0]);
            acc[r][1] = fmaf(H0, c.y, acc[r][1]);
            acc[r][2] = fmaf(H0, c.z, acc[r][2]);
            acc[r][3] = fmaf(H0, c.w, acc[r][3]);
        }
        #pragma unroll
        for (int r = 0; r < 4; ++r) {
            const int j = 2 * (J0 + 92 * r) + pj;
            #pragma unroll
            for (int vv = 0; vv < 4; ++vv)
                Q[(v0 + vv) * NU + j] = acc[r][vv] * 1.2858f;
        }
    }
}

// ---------------- Stage 3: backprojection, view-split x2 + instruction diet ------------
// 2048 blocks: block b -> pixels (b>>1)*256.., view half (b&1). 8192 waves = 8/SIMD.
// Per view: 2 fma (t2) + 2 fma (D) + rcp + fma (fidx) + cvt + med3 + fract + lshl
//           + sub/cmp(abs)/cndmask gate + sub+fma (lerp) + mul (rD^2) + fma (acc).
__global__ __launch_bounds__(256) void bp_kernel(const float* __restrict__ Q,
                                                 const float4* __restrict__ trig,
                                                 float* __restrict__ out) {
    const int b = blockIdx.x;
    const int h = b & 1;                      // view half: [0,360) or [360,720)
    const int p = (b >> 1) * 256 + threadIdx.x;
    const int ix = p >> 9;
    const int jy = p & 511;
    const float dx = 400.0f / 512.0f;         // 0.78125 exact
    const float X  = ((float)ix - 255.5f) * dx;
    const float Y  = ((float)jy - 255.5f) * dx;
    const float nY = -Y;

    float acc = 0.0f;
    const float* qrow = Q + h * 360 * NU;
    const float4* tvp = trig + h * 360;
    #pragma unroll 4
    for (int v = 0; v < 360; ++v) {
        const float4 tv = tvp[v];                  // uniform -> s_load_dwordx4
        float t2 = fmaf(tv.x, X, tv.y * Y);        // t * DSD/DU
        float D  = fmaf(tv.w, X, fmaf(tv.z, nY, 595.0f));   // DSO - s
        float rD = __builtin_amdgcn_rcpf(D);       // v_rcp_f32 (1 ulp)
        float fidx = fmaf(t2, rD, 367.5f);
        int i0 = (int)fidx;
        int i0c = min(max(i0, 0), NU - 2);         // v_med3_i32
        float f = __builtin_amdgcn_fractf(fidx);   // == fidx - floor(fidx); in-bounds == fidx - i0c
        float q0 = qrow[i0c];
        float q1 = qrow[i0c + 1];
        float val = fmaf(f, q1 - q0, q0);
        float g = rD * rD;
        float cen = fidx - 367.5f;                 // in-bounds iff |cen| <= 367.5
        g = (__builtin_fabsf(cen) <= 367.5f) ? g : 0.0f;
        acc = fmaf(g, val, acc);
        qrow += NU;
    }
    // DSO^2 * 0.5 * dbeta folded; scale before the atomic combine
    unsafeAtomicAdd(&out[p], acc * (float)(595.0 * 595.0 * 0.5 * (2.0 * M_PI / 720.0)));
}

extern "C" void kernel_launch(void* const* d_in, const int* in_sizes, int n_in,
                              void* d_out, int out_size, void* d_ws, size_t ws_size,
                              hipStream_t stream) {
    const float* sino = (const float*)d_in[0];
    float* out = (float*)d_out;
    float* Q = (float*)d_ws;                                  // 720*736*4 = 2.12 MB
    float4* trig = (float4*)((char*)d_ws + NV * NU * sizeof(float));  // +11.5 KB

    trig_kernel<<<3, 256, 0, stream>>>(trig);
    filter_kernel<<<NV / 4, 192, 0, stream>>>(sino, Q);
    hipMemsetAsync(out, 0, (size_t)NXY * NXY * sizeof(float), stream);  // atomic targets
    bp_kernel<<<2 * (NXY * NXY) / 256, 256, 0, stream>>>(Q, trig, out);
}